// Round 1
// baseline (251.765 us; speedup 1.0000x reference)
//
#include <hip/hip_runtime.h>

#define IMG_H 1024
#define IMG_W 1024
#define NIMG  16
#define NPIX  16777216.0f   // 16*1024*1024

// ws layout (floats): [0]=bce_sum, [1..16]=inter[img], [17..32]=sum_p[img], [33..48]=sum_t[img]

__global__ __launch_bounds__(256) void dal_main(
    const float* __restrict__ xlogits,
    const float* __restrict__ gmask,
    const float* __restrict__ fuse,
    float* __restrict__ ws)
{
    const int pairsPerImg = IMG_H / 2;
    const int bid = blockIdx.x;
    const int img = bid / pairsPerImg;
    const int pr  = bid - img * pairsPerImg;
    const int e   = pr * 2;                 // even row; block handles rows e, e+1
    const int j0  = (int)threadIdx.x * 4;   // 4 consecutive cols, j0 % 4 == 0

    const float w0 = fuse[0], w1 = fuse[1], w2 = fuse[2];

    const size_t ibase = (size_t)img * IMG_H * IMG_W;
    const float* gi = gmask + ibase;
    const float* xi = xlogits + ibase;

    // Load 4 mask rows (e-1..e+2), cols j0-1..j0+4 (zero padding outside image)
    float gvv[4][6];
    #pragma unroll
    for (int t = 0; t < 4; ++t) {
        int r = e - 1 + t;
        if (r >= 0 && r < IMG_H) {
            const float* row = gi + (size_t)r * IMG_W;
            float4 v = *reinterpret_cast<const float4*>(row + j0);
            gvv[t][0] = (j0 > 0) ? row[j0 - 1] : 0.f;
            gvv[t][1] = v.x; gvv[t][2] = v.y; gvv[t][3] = v.z; gvv[t][4] = v.w;
            gvv[t][5] = (j0 + 4 < IMG_W) ? row[j0 + 4] : 0.f;
        } else {
            #pragma unroll
            for (int k = 0; k < 6; ++k) gvv[t][k] = 0.f;
        }
    }

    // separable rowmin: rm[t][k] = min over cols (j0+k-1 .. j0+k+1) of row e-1+t
    float rm[4][4];
    #pragma unroll
    for (int t = 0; t < 4; ++t)
        #pragma unroll
        for (int k = 0; k < 4; ++k)
            rm[t][k] = fminf(gvv[t][k], fminf(gvv[t][k + 1], gvv[t][k + 2]));

    // bt = g && (min3x3 == 0);  bt[i,j] == stride-1 boundary map
    float bte[4], bto[4];
    #pragma unroll
    for (int k = 0; k < 4; ++k) {
        float cm0 = fminf(rm[0][k], fminf(rm[1][k], rm[2][k]));  // rows e-1..e+1
        float cm1 = fminf(rm[1][k], fminf(rm[2][k], rm[3][k]));  // rows e..e+2
        bte[k] = (gvv[1][k + 1] > 0.5f && cm0 < 0.5f) ? 1.f : 0.f;
        bto[k] = (gvv[2][k + 1] > 0.5f && cm1 < 0.5f) ? 1.f : 0.f;
    }

    // bt4 sample: bt at (4*(e>>2), 4*(j>>2)) == (r4, j0); r4 is e (e%4==0) or e-2 (e%4==2)
    float bt4;
    if ((e & 2) == 0) {
        bt4 = bte[0];
    } else {
        // center row e-2: need rowmins of rows e-3, e-2, e-1 at col j0
        float a0 = 0.f, a1 = 0.f, a2 = 0.f, b0, b1, b2;
        int rA = e - 3;                 // may be -1 (when e == 2)
        if (rA >= 0) {
            const float* row = gi + (size_t)rA * IMG_W;
            a0 = (j0 > 0) ? row[j0 - 1] : 0.f; a1 = row[j0]; a2 = row[j0 + 1];
        }
        {
            const float* row = gi + (size_t)(e - 2) * IMG_W;  // e >= 2 here
            b0 = (j0 > 0) ? row[j0 - 1] : 0.f; b1 = row[j0]; b2 = row[j0 + 1];
        }
        float rmA = fminf(a0, fminf(a1, a2));
        float rmB = fminf(b0, fminf(b1, b2));
        float rmC = rm[0][0];           // row e-1, col j0
        float cm  = fminf(rmA, fminf(rmB, rmC));
        bt4 = (b1 > 0.5f && cm < 0.5f) ? 1.f : 0.f;
    }

    // logits rows e, e+1
    float4 xv0 = *reinterpret_cast<const float4*>(xi + (size_t)e * IMG_W + j0);
    float4 xv1 = *reinterpret_cast<const float4*>(xi + (size_t)(e + 1) * IMG_W + j0);
    float xs0[4] = {xv0.x, xv0.y, xv0.z, xv0.w};
    float xs1[4] = {xv1.x, xv1.y, xv1.z, xv1.w};

    float bce = 0.f, inter = 0.f, sump = 0.f, sumt = 0.f;

    #pragma unroll
    for (int k = 0; k < 4; ++k) {
        // bt2 sample: bt at (e, j0 + (k&2)) for BOTH rows e and e+1
        float b2v = bte[k & 2];
        float fe = w0 * bte[k] + w1 * b2v + w2 * bt4;
        float fo = w0 * bto[k] + w1 * b2v + w2 * bt4;
        float te = (fe > 0.1f) ? 1.f : 0.f;
        float to = (fo > 0.1f) ? 1.f : 0.f;

        {
            float xx = xs0[k];
            float ax = fabsf(xx);
            float em = __expf(-ax);
            bce += fmaxf(xx, 0.f) - xx * te + __logf(1.f + em);
            float r = __builtin_amdgcn_rcpf(1.f + em);
            float p = (xx >= 0.f) ? r : em * r;     // sigmoid(x)
            sump += p; inter += p * te; sumt += te;
        }
        {
            float xx = xs1[k];
            float ax = fabsf(xx);
            float em = __expf(-ax);
            bce += fmaxf(xx, 0.f) - xx * to + __logf(1.f + em);
            float r = __builtin_amdgcn_rcpf(1.f + em);
            float p = (xx >= 0.f) ? r : em * r;
            sump += p; inter += p * to; sumt += to;
        }
    }

    // wave64 reduce, then cross-wave via LDS, then one atomic set per block
    #pragma unroll
    for (int off = 32; off > 0; off >>= 1) {
        bce   += __shfl_down(bce, off);
        inter += __shfl_down(inter, off);
        sump  += __shfl_down(sump, off);
        sumt  += __shfl_down(sumt, off);
    }
    __shared__ float red[4][4];
    const int wid  = threadIdx.x >> 6;
    const int lane = threadIdx.x & 63;
    if (lane == 0) {
        red[0][wid] = bce; red[1][wid] = inter; red[2][wid] = sump; red[3][wid] = sumt;
    }
    __syncthreads();
    if (threadIdx.x == 0) {
        float tb = red[0][0] + red[0][1] + red[0][2] + red[0][3];
        float ti = red[1][0] + red[1][1] + red[1][2] + red[1][3];
        float tp = red[2][0] + red[2][1] + red[2][2] + red[2][3];
        float tt = red[3][0] + red[3][1] + red[3][2] + red[3][3];
        atomicAdd(&ws[0], tb);
        atomicAdd(&ws[1 + img], ti);
        atomicAdd(&ws[17 + img], tp);
        atomicAdd(&ws[33 + img], tt);
    }
}

__global__ void dal_finalize(const float* __restrict__ ws, float* __restrict__ out)
{
    const int l = threadIdx.x;
    float d = 0.f;
    if (l < NIMG) {
        float inter = ws[1 + l], sp = ws[17 + l], st = ws[33 + l];
        d = 1.f - (2.f * inter + 1.f) / (sp + st + 1.f);
    }
    #pragma unroll
    for (int off = 32; off > 0; off >>= 1) d += __shfl_down(d, off);
    if (l == 0) {
        out[0] = ws[0] / NPIX;
        out[1] = d / (float)NIMG;
    }
}

extern "C" void kernel_launch(void* const* d_in, const int* in_sizes, int n_in,
                              void* d_out, int out_size, void* d_ws, size_t ws_size,
                              hipStream_t stream)
{
    const float* x    = (const float*)d_in[0];  // boundary_logits [16,1,1024,1024]
    const float* g    = (const float*)d_in[1];  // gtmasks        [16,1024,1024]
    const float* fuse = (const float*)d_in[2];  // fuse_kernel    [3]
    float* out = (float*)d_out;
    float* ws  = (float*)d_ws;

    hipMemsetAsync(ws, 0, 49 * sizeof(float), stream);

    const int blocks = NIMG * (IMG_H / 2);  // 8192
    dal_main<<<blocks, 256, 0, stream>>>(x, g, fuse, ws);
    dal_finalize<<<1, 64, 0, stream>>>(ws, out);
}

// Round 2
// 44.303 us; speedup vs baseline: 5.6827x; 5.6827x over previous
//
#include <hip/hip_runtime.h>

#define IMG_H 1024
#define IMG_W 1024
#define NIMG  16
#define NPIX  16777216.0f   // 16*1024*1024
#define NBLK  8192          // NIMG * IMG_H/2

// ws layout (floats), one slot per block, no atomics:
//   [0      .. 8191 ]  bce partial
//   [8192   .. 16383]  inter partial
//   [16384  .. 24575]  sum_p partial
//   [24576  .. 32767]  sum_t partial

__global__ __launch_bounds__(256) void dal_main(
    const float* __restrict__ xlogits,
    const float* __restrict__ gmask,
    const float* __restrict__ fuse,
    float* __restrict__ ws)
{
    const int pairsPerImg = IMG_H / 2;
    const int bid = blockIdx.x;
    const int img = bid / pairsPerImg;
    const int pr  = bid - img * pairsPerImg;
    const int e   = pr * 2;                 // even row; block handles rows e, e+1
    const int j0  = (int)threadIdx.x * 4;   // 4 consecutive cols, j0 % 4 == 0

    const float w0 = fuse[0], w1 = fuse[1], w2 = fuse[2];

    const size_t ibase = (size_t)img * IMG_H * IMG_W;
    const float* gi = gmask + ibase;
    const float* xi = xlogits + ibase;

    // Load 4 mask rows (e-1..e+2), cols j0-1..j0+4 (zero padding outside image)
    float gvv[4][6];
    #pragma unroll
    for (int t = 0; t < 4; ++t) {
        int r = e - 1 + t;
        if (r >= 0 && r < IMG_H) {
            const float* row = gi + (size_t)r * IMG_W;
            float4 v = *reinterpret_cast<const float4*>(row + j0);
            gvv[t][0] = (j0 > 0) ? row[j0 - 1] : 0.f;
            gvv[t][1] = v.x; gvv[t][2] = v.y; gvv[t][3] = v.z; gvv[t][4] = v.w;
            gvv[t][5] = (j0 + 4 < IMG_W) ? row[j0 + 4] : 0.f;
        } else {
            #pragma unroll
            for (int k = 0; k < 6; ++k) gvv[t][k] = 0.f;
        }
    }

    // separable rowmin: rm[t][k] = min over cols (j0+k-1 .. j0+k+1) of row e-1+t
    float rm[4][4];
    #pragma unroll
    for (int t = 0; t < 4; ++t)
        #pragma unroll
        for (int k = 0; k < 4; ++k)
            rm[t][k] = fminf(gvv[t][k], fminf(gvv[t][k + 1], gvv[t][k + 2]));

    // bt = g && (min3x3 == 0);  bt[i,j] == stride-1 boundary map
    float bte[4], bto[4];
    #pragma unroll
    for (int k = 0; k < 4; ++k) {
        float cm0 = fminf(rm[0][k], fminf(rm[1][k], rm[2][k]));  // rows e-1..e+1
        float cm1 = fminf(rm[1][k], fminf(rm[2][k], rm[3][k]));  // rows e..e+2
        bte[k] = (gvv[1][k + 1] > 0.5f && cm0 < 0.5f) ? 1.f : 0.f;
        bto[k] = (gvv[2][k + 1] > 0.5f && cm1 < 0.5f) ? 1.f : 0.f;
    }

    // bt4 sample: bt at (4*(e>>2), 4*(j>>2)) == (r4, j0); r4 is e (e%4==0) or e-2 (e%4==2)
    float bt4;
    if ((e & 2) == 0) {
        bt4 = bte[0];
    } else {
        // center row e-2: need rowmins of rows e-3, e-2, e-1 at col j0
        float a0 = 0.f, a1 = 0.f, a2 = 0.f, b0, b1, b2;
        int rA = e - 3;                 // may be -1 (when e == 2)
        if (rA >= 0) {
            const float* row = gi + (size_t)rA * IMG_W;
            a0 = (j0 > 0) ? row[j0 - 1] : 0.f; a1 = row[j0]; a2 = row[j0 + 1];
        }
        {
            const float* row = gi + (size_t)(e - 2) * IMG_W;  // e >= 2 here
            b0 = (j0 > 0) ? row[j0 - 1] : 0.f; b1 = row[j0]; b2 = row[j0 + 1];
        }
        float rmA = fminf(a0, fminf(a1, a2));
        float rmB = fminf(b0, fminf(b1, b2));
        float rmC = rm[0][0];           // row e-1, col j0
        float cm  = fminf(rmA, fminf(rmB, rmC));
        bt4 = (b1 > 0.5f && cm < 0.5f) ? 1.f : 0.f;
    }

    // logits rows e, e+1
    float4 xv0 = *reinterpret_cast<const float4*>(xi + (size_t)e * IMG_W + j0);
    float4 xv1 = *reinterpret_cast<const float4*>(xi + (size_t)(e + 1) * IMG_W + j0);
    float xs0[4] = {xv0.x, xv0.y, xv0.z, xv0.w};
    float xs1[4] = {xv1.x, xv1.y, xv1.z, xv1.w};

    float bce = 0.f, inter = 0.f, sump = 0.f, sumt = 0.f;

    #pragma unroll
    for (int k = 0; k < 4; ++k) {
        // bt2 sample: bt at (e, j0 + (k&2)) for BOTH rows e and e+1
        float b2v = bte[k & 2];
        float fe = w0 * bte[k] + w1 * b2v + w2 * bt4;
        float fo = w0 * bto[k] + w1 * b2v + w2 * bt4;
        float te = (fe > 0.1f) ? 1.f : 0.f;
        float to = (fo > 0.1f) ? 1.f : 0.f;

        {
            float xx = xs0[k];
            float ax = fabsf(xx);
            float em = __expf(-ax);
            bce += fmaxf(xx, 0.f) - xx * te + __logf(1.f + em);
            float r = __builtin_amdgcn_rcpf(1.f + em);
            float p = (xx >= 0.f) ? r : em * r;     // sigmoid(x)
            sump += p; inter += p * te; sumt += te;
        }
        {
            float xx = xs1[k];
            float ax = fabsf(xx);
            float em = __expf(-ax);
            bce += fmaxf(xx, 0.f) - xx * to + __logf(1.f + em);
            float r = __builtin_amdgcn_rcpf(1.f + em);
            float p = (xx >= 0.f) ? r : em * r;
            sump += p; inter += p * to; sumt += to;
        }
    }

    // wave64 reduce, then cross-wave via LDS, then ONE plain store set per block
    #pragma unroll
    for (int off = 32; off > 0; off >>= 1) {
        bce   += __shfl_down(bce, off);
        inter += __shfl_down(inter, off);
        sump  += __shfl_down(sump, off);
        sumt  += __shfl_down(sumt, off);
    }
    __shared__ float red[4][4];
    const int wid  = threadIdx.x >> 6;
    const int lane = threadIdx.x & 63;
    if (lane == 0) {
        red[0][wid] = bce; red[1][wid] = inter; red[2][wid] = sump; red[3][wid] = sumt;
    }
    __syncthreads();
    if (threadIdx.x == 0) {
        ws[bid]            = red[0][0] + red[0][1] + red[0][2] + red[0][3];
        ws[NBLK + bid]     = red[1][0] + red[1][1] + red[1][2] + red[1][3];
        ws[2 * NBLK + bid] = red[2][0] + red[2][1] + red[2][2] + red[2][3];
        ws[3 * NBLK + bid] = red[3][0] + red[3][1] + red[3][2] + red[3][3];
    }
}

// 1 block, 1024 threads. Wave w (threads 64w..64w+63) covers block-ids
// [512w, 512w+512) == exactly image w. Each thread sums 8 consecutive slots
// (2 x float4) per array, wave-reduces, then thread 0 combines 16 waves.
__global__ __launch_bounds__(1024) void dal_finalize(
    const float* __restrict__ ws, float* __restrict__ out)
{
    const int t    = threadIdx.x;
    const int wv   = t >> 6;      // wave id == image id
    const int lane = t & 63;
    const int i0   = t * 8;       // 32B aligned

    float bce = 0.f, inter = 0.f, sump = 0.f, sumt = 0.f;
    {
        float4 a = *reinterpret_cast<const float4*>(ws + i0);
        float4 b = *reinterpret_cast<const float4*>(ws + i0 + 4);
        bce = (a.x + a.y) + (a.z + a.w) + (b.x + b.y) + (b.z + b.w);
    }
    {
        float4 a = *reinterpret_cast<const float4*>(ws + NBLK + i0);
        float4 b = *reinterpret_cast<const float4*>(ws + NBLK + i0 + 4);
        inter = (a.x + a.y) + (a.z + a.w) + (b.x + b.y) + (b.z + b.w);
    }
    {
        float4 a = *reinterpret_cast<const float4*>(ws + 2 * NBLK + i0);
        float4 b = *reinterpret_cast<const float4*>(ws + 2 * NBLK + i0 + 4);
        sump = (a.x + a.y) + (a.z + a.w) + (b.x + b.y) + (b.z + b.w);
    }
    {
        float4 a = *reinterpret_cast<const float4*>(ws + 3 * NBLK + i0);
        float4 b = *reinterpret_cast<const float4*>(ws + 3 * NBLK + i0 + 4);
        sumt = (a.x + a.y) + (a.z + a.w) + (b.x + b.y) + (b.z + b.w);
    }

    #pragma unroll
    for (int off = 32; off > 0; off >>= 1) {
        bce   += __shfl_down(bce, off);
        inter += __shfl_down(inter, off);
        sump  += __shfl_down(sump, off);
        sumt  += __shfl_down(sumt, off);
    }

    __shared__ float sb[16], sd[16];
    if (lane == 0) {
        sb[wv] = bce;
        sd[wv] = 1.f - (2.f * inter + 1.f) / (sump + sumt + 1.f);
    }
    __syncthreads();
    if (t == 0) {
        float tb = 0.f, td = 0.f;
        #pragma unroll
        for (int i = 0; i < NIMG; ++i) { tb += sb[i]; td += sd[i]; }
        out[0] = tb / NPIX;
        out[1] = td / (float)NIMG;
    }
}

extern "C" void kernel_launch(void* const* d_in, const int* in_sizes, int n_in,
                              void* d_out, int out_size, void* d_ws, size_t ws_size,
                              hipStream_t stream)
{
    const float* x    = (const float*)d_in[0];  // boundary_logits [16,1,1024,1024]
    const float* g    = (const float*)d_in[1];  // gtmasks        [16,1024,1024]
    const float* fuse = (const float*)d_in[2];  // fuse_kernel    [3]
    float* out = (float*)d_out;
    float* ws  = (float*)d_ws;

    dal_main<<<NBLK, 256, 0, stream>>>(x, g, fuse, ws);
    dal_finalize<<<1, 1024, 0, stream>>>(ws, out);
}

// Round 3
// 34.937 us; speedup vs baseline: 7.2063x; 1.2681x over previous
//
#include <hip/hip_runtime.h>

#define IMG_H 1024
#define IMG_W 1024
#define NIMG  16
#define NPIX  16777216.0f   // 16*1024*1024
#define QPI   256           // row-quads per image (1024/4)
#define NBLK  4096          // NIMG * QPI

// ws layout (floats), one slot per block, no atomics:
//   [0      .. 4095 ]  bce partial
//   [4096   .. 8191 ]  inter partial
//   [8192   .. 12287]  sum_p partial
//   [12288  .. 16383]  sum_t partial

__global__ __launch_bounds__(256) void dal_main(
    const float* __restrict__ xlogits,
    const float* __restrict__ gmask,
    const float* __restrict__ fuse,
    float* __restrict__ ws)
{
    const int bid  = blockIdx.x;
    const int img  = bid >> 8;         // / QPI
    const int q    = bid & 255;
    const int r0   = q << 2;           // rows r0 .. r0+3, r0 % 4 == 0
    const int tid  = (int)threadIdx.x;
    const int lane = tid & 63;
    const int j0   = tid * 4;          // 4 consecutive cols, j0 % 4 == 0

    const float w0 = fuse[0], w1 = fuse[1], w2 = fuse[2];

    const size_t ibase = (size_t)img * (IMG_H * IMG_W);
    const float* gi = gmask + ibase;
    const float* xi = xlogits + ibase;

    // Stream mask rows r0-1 .. r0+4; keep rowmins + center values only.
    // Column halos via wave shuffles; wave-edge lanes do a (rare) L1-hit load.
    float rm[6][4];   // rowmin over cols (j0+k-1 .. j0+k+1)
    float cv[4][4];   // g center values, rows r0..r0+3, cols j0..j0+3
    #pragma unroll
    for (int t = 0; t < 6; ++t) {
        const int r = r0 - 1 + t;
        float4 v;
        float lft, rgt;
        if (r >= 0 && r < IMG_H) {     // block-uniform branch
            const float* row = gi + (size_t)r * IMG_W;
            v = *reinterpret_cast<const float4*>(row + j0);
            lft = __shfl_up(v.w, 1);
            if (lane == 0)  lft = (j0 == 0) ? 0.f : row[j0 - 1];
            rgt = __shfl_down(v.x, 1);
            if (lane == 63) rgt = (j0 + 4 >= IMG_W) ? 0.f : row[j0 + 4];
        } else {
            v.x = v.y = v.z = v.w = 0.f; lft = 0.f; rgt = 0.f;
        }
        rm[t][0] = fminf(lft, fminf(v.x, v.y));
        rm[t][1] = fminf(v.x, fminf(v.y, v.z));
        rm[t][2] = fminf(v.y, fminf(v.z, v.w));
        rm[t][3] = fminf(v.z, fminf(v.w, rgt));
        if (t >= 1 && t <= 4) {
            cv[t - 1][0] = v.x; cv[t - 1][1] = v.y;
            cv[t - 1][2] = v.z; cv[t - 1][3] = v.w;
        }
    }

    // bt (stride-1 boundary map) for rows r0..r0+3:
    // bt = (g == 1) && (min over 3x3 neighborhood == 0)
    float bt[4][4];
    #pragma unroll
    for (int r = 0; r < 4; ++r)
        #pragma unroll
        for (int k = 0; k < 4; ++k) {
            float cm = fminf(rm[r][k], fminf(rm[r + 1][k], rm[r + 2][k]));
            bt[r][k] = (cv[r][k] > 0.5f && cm < 0.5f) ? 1.f : 0.f;
        }

    // bt4 sample for every pixel in this quad/strip: bt at (r0, j0)
    const float bt4v = bt[0][0];

    float bce = 0.f, inter = 0.f, sump = 0.f, sumt = 0.f;

    #pragma unroll
    for (int r = 0; r < 4; ++r) {
        float4 xv = *reinterpret_cast<const float4*>(xi + (size_t)(r0 + r) * IMG_W + j0);
        float xs[4] = {xv.x, xv.y, xv.z, xv.w};
        #pragma unroll
        for (int k = 0; k < 4; ++k) {
            // bt2 sample: bt at (r0 + (r&~1), j0 + (k&~1))
            float f = w0 * bt[r][k] + w1 * bt[r & ~1][k & 2] + w2 * bt4v;
            float tg = (f > 0.1f) ? 1.f : 0.f;
            float xx = xs[k];
            float ax = fabsf(xx);
            float em = __expf(-ax);
            bce += fmaxf(xx, 0.f) - xx * tg + __logf(1.f + em);
            float rc = __builtin_amdgcn_rcpf(1.f + em);
            float p  = (xx >= 0.f) ? rc : em * rc;   // sigmoid(x)
            sump += p; inter += p * tg; sumt += tg;
        }
    }

    // wave64 reduce, then cross-wave via LDS, then ONE plain store set per block
    #pragma unroll
    for (int off = 32; off > 0; off >>= 1) {
        bce   += __shfl_down(bce, off);
        inter += __shfl_down(inter, off);
        sump  += __shfl_down(sump, off);
        sumt  += __shfl_down(sumt, off);
    }
    __shared__ float red[4][4];
    const int wid = tid >> 6;
    if (lane == 0) {
        red[0][wid] = bce; red[1][wid] = inter; red[2][wid] = sump; red[3][wid] = sumt;
    }
    __syncthreads();
    if (tid == 0) {
        ws[bid]            = red[0][0] + red[0][1] + red[0][2] + red[0][3];
        ws[NBLK + bid]     = red[1][0] + red[1][1] + red[1][2] + red[1][3];
        ws[2 * NBLK + bid] = red[2][0] + red[2][1] + red[2][2] + red[2][3];
        ws[3 * NBLK + bid] = red[3][0] + red[3][1] + red[3][2] + red[3][3];
    }
}

// 1 block, 1024 threads. Wave w (threads 64w..64w+63) covers block-ids
// [256w, 256w+256) == exactly image w (QPI = 256 quads per image).
// Each thread loads 1 float4 per array, wave-reduces, thread 0 combines.
__global__ __launch_bounds__(1024) void dal_finalize(
    const float* __restrict__ ws, float* __restrict__ out)
{
    const int t    = (int)threadIdx.x;
    const int wv   = t >> 6;      // wave id == image id
    const int lane = t & 63;
    const int i0   = t * 4;

    float4 a0 = *reinterpret_cast<const float4*>(ws + i0);
    float4 a1 = *reinterpret_cast<const float4*>(ws + NBLK + i0);
    float4 a2 = *reinterpret_cast<const float4*>(ws + 2 * NBLK + i0);
    float4 a3 = *reinterpret_cast<const float4*>(ws + 3 * NBLK + i0);

    float bce   = (a0.x + a0.y) + (a0.z + a0.w);
    float inter = (a1.x + a1.y) + (a1.z + a1.w);
    float sump  = (a2.x + a2.y) + (a2.z + a2.w);
    float sumt  = (a3.x + a3.y) + (a3.z + a3.w);

    #pragma unroll
    for (int off = 32; off > 0; off >>= 1) {
        bce   += __shfl_down(bce, off);
        inter += __shfl_down(inter, off);
        sump  += __shfl_down(sump, off);
        sumt  += __shfl_down(sumt, off);
    }

    __shared__ float sb[16], sd[16];
    if (lane == 0) {
        sb[wv] = bce;
        sd[wv] = 1.f - (2.f * inter + 1.f) / (sump + sumt + 1.f);
    }
    __syncthreads();
    if (t == 0) {
        float tb = 0.f, td = 0.f;
        #pragma unroll
        for (int i = 0; i < NIMG; ++i) { tb += sb[i]; td += sd[i]; }
        out[0] = tb / NPIX;
        out[1] = td / (float)NIMG;
    }
}

extern "C" void kernel_launch(void* const* d_in, const int* in_sizes, int n_in,
                              void* d_out, int out_size, void* d_ws, size_t ws_size,
                              hipStream_t stream)
{
    const float* x    = (const float*)d_in[0];  // boundary_logits [16,1,1024,1024]
    const float* g    = (const float*)d_in[1];  // gtmasks        [16,1024,1024]
    const float* fuse = (const float*)d_in[2];  // fuse_kernel    [3]
    float* out = (float*)d_out;
    float* ws  = (float*)d_ws;

    dal_main<<<NBLK, 256, 0, stream>>>(x, g, fuse, ws);
    dal_finalize<<<1, 1024, 0, stream>>>(ws, out);
}

// Round 5
// 33.265 us; speedup vs baseline: 7.5684x; 1.0502x over previous
//
#include <hip/hip_runtime.h>

#define IMG_H 1024
#define IMG_W 1024
#define NIMG  16
#define NPIX  16777216.0f   // 16*1024*1024
#define QPI   256           // row-quads per image (1024/4)
#define NBLK  4096          // NIMG * QPI
#define LOG2E 1.44269504088896340736f
#define LN2   0.69314718055994530942f

// ws layout (floats), one slot per block, no atomics:
//   [0      .. 4095 ]  bce partial
//   [4096   .. 8191 ]  inter partial
//   [8192   .. 12287]  sum_p partial
//   [12288  .. 16383]  sum_t partial

__global__ __launch_bounds__(256) void dal_main(
    const float* __restrict__ xlogits,
    const float* __restrict__ gmask,
    const float* __restrict__ fuse,
    float* __restrict__ ws)
{
    const int bid  = blockIdx.x;
    const int img  = bid >> 8;         // / QPI
    const int q    = bid & 255;
    const int r0   = q << 2;           // rows r0 .. r0+3, r0 % 4 == 0
    const int tid  = (int)threadIdx.x;
    const int lane = tid & 63;
    const int j0   = tid * 4;          // 4 consecutive cols, j0 % 4 == 0

    const float w0 = fuse[0], w1 = fuse[1], w2 = fuse[2];

    const size_t ibase = (size_t)img * (IMG_H * IMG_W);
    const float* gi = gmask + ibase;
    const float* xi = xlogits + ibase;

    // clamped halo column addresses + validity predicates (computed once)
    const int  jl   = (j0 > 0) ? (j0 - 1) : 0;
    const int  jr   = (j0 + 4 < IMG_W) ? (j0 + 4) : (IMG_W - 1);
    const bool hasL = (j0 > 0);
    const bool hasR = (j0 + 4 < IMG_W);

    // issue logits loads early (independent of everything below)
    const float* xrow = xi + (size_t)r0 * IMG_W + j0;
    float4 xv0 = *reinterpret_cast<const float4*>(xrow);
    float4 xv1 = *reinterpret_cast<const float4*>(xrow + IMG_W);
    float4 xv2 = *reinterpret_cast<const float4*>(xrow + 2 * IMG_W);
    float4 xv3 = *reinterpret_cast<const float4*>(xrow + 3 * IMG_W);

    // mask rows r0-1 .. r0+4: rowmin over (j0+k-1 .. j0+k+1), convergent code,
    // halos via clamped scalar loads + cndmask (no shuffles, no lane branches)
    float rm[6][4];   // rowmins
    float cv[4][4];   // center values, rows r0..r0+3
    #pragma unroll
    for (int t = 0; t < 6; ++t) {
        const int r = r0 - 1 + t;
        float vx = 0.f, vy = 0.f, vz = 0.f, vw = 0.f, lf = 0.f, rg = 0.f;
        if (r >= 0 && r < IMG_H) {     // block-uniform branch (q==0 / q==255 only)
            const float* row = gi + (size_t)r * IMG_W;
            float4 v = *reinterpret_cast<const float4*>(row + j0);
            float l = row[jl];
            float g = row[jr];
            vx = v.x; vy = v.y; vz = v.z; vw = v.w;
            lf = hasL ? l : 0.f;
            rg = hasR ? g : 0.f;
        }
        rm[t][0] = fminf(lf, fminf(vx, vy));
        rm[t][1] = fminf(vx, fminf(vy, vz));
        rm[t][2] = fminf(vy, fminf(vz, vw));
        rm[t][3] = fminf(vz, fminf(vw, rg));
        if (t >= 1 && t <= 4) {
            cv[t - 1][0] = vx; cv[t - 1][1] = vy;
            cv[t - 1][2] = vz; cv[t - 1][3] = vw;
        }
    }

    // bt (stride-1 boundary map): bt = (g == 1) && (min3x3 == 0)
    float bt[4][4];
    #pragma unroll
    for (int r = 0; r < 4; ++r)
        #pragma unroll
        for (int k = 0; k < 4; ++k) {
            float cm = fminf(rm[r][k], fminf(rm[r + 1][k], rm[r + 2][k]));
            bt[r][k] = (cv[r][k] > 0.5f && cm < 0.5f) ? 1.f : 0.f;
        }

    // bt4 sample for the whole quad is bt(r0, j0) = bt[0][0];
    // bt2 sample for (r,k) is bt(r0+(r&~1), j0+(k&~1)).
    // Precompute base2[rp][kp] = w1*bt2 + w2*bt4 (4 combos).
    const float wb4 = w2 * bt[0][0];
    float base2[2][2];
    base2[0][0] = fmaf(w1, bt[0][0], wb4);
    base2[0][1] = fmaf(w1, bt[0][2], wb4);
    base2[1][0] = fmaf(w1, bt[2][0], wb4);
    base2[1][1] = fmaf(w1, bt[2][2], wb4);

    // Per-pixel: f = w0*bt + base2;  t = f > 0.1
    // bce_px = ln2*log2(1+e^x) - x*t   (softplus identity, ln2 deferred)
    // p = u/(1+u), u = e^x;  sum_t via ballot+popcount (SALU, off the VALU pipe)
    float l2 = 0.f, xt = 0.f, inter = 0.f, sump = 0.f;
    int   st = 0;

    auto px = [&](float x, float btv, float b2v) {
        float f = fmaf(w0, btv, b2v);
        bool  c = f > 0.1f;
        st += (int)__popcll(__ballot(c));
        float u   = __builtin_amdgcn_exp2f(x * LOG2E);   // e^x
        float opu = 1.f + u;
        float p   = u * __builtin_amdgcn_rcpf(opu);      // sigmoid(x)
        l2   += __builtin_amdgcn_logf(opu);              // log2(1+e^x)
        sump += p;
        xt   += c ? x : 0.f;
        inter+= c ? p : 0.f;
    };

    px(xv0.x, bt[0][0], base2[0][0]); px(xv0.y, bt[0][1], base2[0][0]);
    px(xv0.z, bt[0][2], base2[0][1]); px(xv0.w, bt[0][3], base2[0][1]);
    px(xv1.x, bt[1][0], base2[0][0]); px(xv1.y, bt[1][1], base2[0][0]);
    px(xv1.z, bt[1][2], base2[0][1]); px(xv1.w, bt[1][3], base2[0][1]);
    px(xv2.x, bt[2][0], base2[1][0]); px(xv2.y, bt[2][1], base2[1][0]);
    px(xv2.z, bt[2][2], base2[1][1]); px(xv2.w, bt[2][3], base2[1][1]);
    px(xv3.x, bt[3][0], base2[1][0]); px(xv3.y, bt[3][1], base2[1][0]);
    px(xv3.z, bt[3][2], base2[1][1]); px(xv3.w, bt[3][3], base2[1][1]);

    float bce = fmaf(LN2, l2, -xt);

    // wave64 reduce (3 floats; sum_t is wave-uniform already), cross-wave via LDS
    #pragma unroll
    for (int off = 32; off > 0; off >>= 1) {
        bce   += __shfl_down(bce, off);
        inter += __shfl_down(inter, off);
        sump  += __shfl_down(sump, off);
    }
    __shared__ float red[4][4];
    const int wid = tid >> 6;
    if (lane == 0) {
        red[0][wid] = bce; red[1][wid] = inter;
        red[2][wid] = sump; red[3][wid] = (float)st;
    }
    __syncthreads();
    if (tid == 0) {
        ws[bid]            = red[0][0] + red[0][1] + red[0][2] + red[0][3];
        ws[NBLK + bid]     = red[1][0] + red[1][1] + red[1][2] + red[1][3];
        ws[2 * NBLK + bid] = red[2][0] + red[2][1] + red[2][2] + red[2][3];
        ws[3 * NBLK + bid] = red[3][0] + red[3][1] + red[3][2] + red[3][3];
    }
}

// 1 block, 1024 threads. Wave w (threads 64w..64w+63) covers block-ids
// [256w, 256w+256) == exactly image w (QPI = 256 quads per image).
__global__ __launch_bounds__(1024) void dal_finalize(
    const float* __restrict__ ws, float* __restrict__ out)
{
    const int t    = (int)threadIdx.x;
    const int wv   = t >> 6;      // wave id == image id
    const int lane = t & 63;
    const int i0   = t * 4;

    float4 a0 = *reinterpret_cast<const float4*>(ws + i0);
    float4 a1 = *reinterpret_cast<const float4*>(ws + NBLK + i0);
    float4 a2 = *reinterpret_cast<const float4*>(ws + 2 * NBLK + i0);
    float4 a3 = *reinterpret_cast<const float4*>(ws + 3 * NBLK + i0);

    float bce   = (a0.x + a0.y) + (a0.z + a0.w);
    float inter = (a1.x + a1.y) + (a1.z + a1.w);
    float sump  = (a2.x + a2.y) + (a2.z + a2.w);
    float sumt  = (a3.x + a3.y) + (a3.z + a3.w);

    #pragma unroll
    for (int off = 32; off > 0; off >>= 1) {
        bce   += __shfl_down(bce, off);
        inter += __shfl_down(inter, off);
        sump  += __shfl_down(sump, off);
        sumt  += __shfl_down(sumt, off);
    }

    __shared__ float sb[16], sd[16];
    if (lane == 0) {
        sb[wv] = bce;
        sd[wv] = 1.f - (2.f * inter + 1.f) / (sump + sumt + 1.f);
    }
    __syncthreads();
    if (t == 0) {
        float tb = 0.f, td = 0.f;
        #pragma unroll
        for (int i = 0; i < NIMG; ++i) { tb += sb[i]; td += sd[i]; }
        out[0] = tb / NPIX;
        out[1] = td / (float)NIMG;
    }
}

extern "C" void kernel_launch(void* const* d_in, const int* in_sizes, int n_in,
                              void* d_out, int out_size, void* d_ws, size_t ws_size,
                              hipStream_t stream)
{
    const float* x    = (const float*)d_in[0];  // boundary_logits [16,1,1024,1024]
    const float* g    = (const float*)d_in[1];  // gtmasks        [16,1024,1024]
    const float* fuse = (const float*)d_in[2];  // fuse_kernel    [3]
    float* out = (float*)d_out;
    float* ws  = (float*)d_ws;

    dal_main<<<NBLK, 256, 0, stream>>>(x, g, fuse, ws);
    dal_finalize<<<1, 1024, 0, stream>>>(ws, out);
}

// Round 6
// 31.121 us; speedup vs baseline: 8.0898x; 1.0689x over previous
//
#include <hip/hip_runtime.h>

#define IMG_H 1024
#define IMG_W 1024
#define NIMG  16
#define NPIX  16777216.0f   // 16*1024*1024
#define SPI   128           // 8-row strips per image (1024/8)
#define NBLK  2048          // NIMG * SPI
#define LOG2E 1.44269504088896340736f
#define LN2   0.69314718055994530942f

// ws layout: one float4 per block: {bce, inter, sum_p, sum_t}. 2048*16B = 32 KB.

__global__ __launch_bounds__(256) void dal_main(
    const float* __restrict__ xlogits,
    const float* __restrict__ gmask,
    const float* __restrict__ fuse,
    float4* __restrict__ ws4)
{
    const int bid  = blockIdx.x;
    const int img  = bid >> 7;          // / SPI
    const int q    = bid & 127;
    const int r0   = q << 3;            // rows r0 .. r0+7, r0 % 8 == 0
    const int tid  = (int)threadIdx.x;
    const int lane = tid & 63;
    const int j0   = tid * 4;           // 4 cols per thread, j0 % 4 == 0

    const float w0 = fuse[0], w1 = fuse[1], w2 = fuse[2];

    const size_t ibase = (size_t)img * (IMG_H * IMG_W);
    const float* gi = gmask + ibase;
    const float* xi = xlogits + ibase;

    // Overlapping-load halo scheme: per row, two float4 loads at j0-1 and j0+1
    // (clamped for edge lanes, fixed up with cndmask). Covers cols j0-1..j0+4.
    const int  jl   = (j0 > 0) ? (j0 - 1) : 0;
    const int  jr1  = (j0 + 4 < IMG_W) ? (j0 + 1) : (IMG_W - 4);
    const bool hasL = (j0 > 0);
    const bool hasR = (j0 + 4 < IMG_W);

    // Mask rows r0-1 .. r0+8: rowmin over (j0+k-1 .. j0+k+1) + center values.
    float rm[10][4];
    float cv[8][4];
    #pragma unroll
    for (int t = 0; t < 10; ++t) {
        const int r = r0 - 1 + t;
        float c0 = 0.f, c1 = 0.f, c2 = 0.f, c3 = 0.f, c4 = 0.f, c5 = 0.f;
        if (r >= 0 && r < IMG_H) {      // block-uniform (first/last strip only)
            const float* row = gi + (size_t)r * IMG_W;
            float4 a = *reinterpret_cast<const float4*>(row + jl);
            float4 b = *reinterpret_cast<const float4*>(row + jr1);
            // interior: a = cols j0-1..j0+2, b = cols j0+1..j0+4
            c0 = hasL ? a.x : 0.f;      // col j0-1 (pad 0 at left edge)
            c1 = hasL ? a.y : a.x;      // col j0
            c2 = hasL ? a.z : a.y;      // col j0+1
            c3 = hasL ? a.w : a.z;      // col j0+2
            c4 = hasR ? b.z : b.w;      // col j0+3
            c5 = hasR ? b.w : 0.f;      // col j0+4 (pad 0 at right edge)
        }
        rm[t][0] = fminf(c0, fminf(c1, c2));
        rm[t][1] = fminf(c1, fminf(c2, c3));
        rm[t][2] = fminf(c2, fminf(c3, c4));
        rm[t][3] = fminf(c3, fminf(c4, c5));
        if (t >= 1 && t <= 8) {
            cv[t - 1][0] = c1; cv[t - 1][1] = c2;
            cv[t - 1][2] = c3; cv[t - 1][3] = c4;
        }
    }

    // bt (stride-1 boundary map): bt = (g == 1) && (min3x3 == 0)
    float bt[8][4];
    #pragma unroll
    for (int r = 0; r < 8; ++r)
        #pragma unroll
        for (int k = 0; k < 4; ++k) {
            float cm = fminf(rm[r][k], fminf(rm[r + 1][k], rm[r + 2][k]));
            bt[r][k] = (cv[r][k] > 0.5f && cm < 0.5f) ? 1.f : 0.f;
        }

    // bt4 sample: rows r0..r0+3 -> bt(r0, j0); rows r0+4..r0+7 -> bt(r0+4, j0)
    // bt2 sample: bt(r0+(r&~1), j0+(k&~1))
    // base2[rp][kp] = w1*bt2 + w2*bt4 for row-pair rp, col-pair kp
    const float wb4A = w2 * bt[0][0];
    const float wb4B = w2 * bt[4][0];
    float base2[4][2];
    #pragma unroll
    for (int rp = 0; rp < 4; ++rp) {
        const float wb = (rp < 2) ? wb4A : wb4B;
        base2[rp][0] = fmaf(w1, bt[2 * rp][0], wb);
        base2[rp][1] = fmaf(w1, bt[2 * rp][2], wb);
    }

    // Per-pixel: f = w0*bt + base2;  t = f > 0.1
    // bce_px = ln2*log2(1+e^x) - x*t ; p = u/(1+u), u = e^x
    // sum_t via ballot+popcount (SALU). Dual accumulators (row parity) for ILP.
    float l2[2]  = {0.f, 0.f}, xt[2] = {0.f, 0.f};
    float itr[2] = {0.f, 0.f}, sp[2] = {0.f, 0.f};
    int st = 0;

    auto px = [&](float x, float btv, float b2v, int a) {
        float f = fmaf(w0, btv, b2v);
        bool  c = f > 0.1f;
        st += (int)__popcll(__ballot(c));
        float u   = __builtin_amdgcn_exp2f(x * LOG2E);   // e^x
        float opu = 1.f + u;
        float p   = u * __builtin_amdgcn_rcpf(opu);      // sigmoid(x)
        l2[a]  += __builtin_amdgcn_logf(opu);            // log2(1+e^x)
        sp[a]  += p;
        xt[a]  += c ? x : 0.f;
        itr[a] += c ? p : 0.f;
    };

    const float* xrow = xi + (size_t)r0 * IMG_W + j0;
    #pragma unroll
    for (int r = 0; r < 8; ++r) {
        float4 xv = *reinterpret_cast<const float4*>(xrow + (size_t)r * IMG_W);
        const int   rp = r >> 1;
        const int   a  = r & 1;
        const float bA = base2[rp][0];
        const float bB = base2[rp][1];
        px(xv.x, bt[r][0], bA, a);
        px(xv.y, bt[r][1], bA, a);
        px(xv.z, bt[r][2], bB, a);
        px(xv.w, bt[r][3], bB, a);
    }

    float bce   = fmaf(LN2, l2[0] + l2[1], -(xt[0] + xt[1]));
    float inter = itr[0] + itr[1];
    float sump  = sp[0] + sp[1];

    // wave64 reduce (st is already wave-uniform via ballot), cross-wave via LDS
    #pragma unroll
    for (int off = 32; off > 0; off >>= 1) {
        bce   += __shfl_down(bce, off);
        inter += __shfl_down(inter, off);
        sump  += __shfl_down(sump, off);
    }
    __shared__ float red[4][4];
    const int wid = tid >> 6;
    if (lane == 0) {
        red[0][wid] = bce; red[1][wid] = inter;
        red[2][wid] = sump; red[3][wid] = (float)st;
    }
    __syncthreads();
    if (tid == 0) {
        float4 o;
        o.x = red[0][0] + red[0][1] + red[0][2] + red[0][3];
        o.y = red[1][0] + red[1][1] + red[1][2] + red[1][3];
        o.z = red[2][0] + red[2][1] + red[2][2] + red[2][3];
        o.w = red[3][0] + red[3][1] + red[3][2] + red[3][3];
        ws4[bid] = o;
    }
}

// 1 block, 1024 threads. Thread t loads slots 2t, 2t+1 (same image: both in
// [128w, 128w+128) for wave w = t>>6). Wave-reduce, per-image dice, combine.
__global__ __launch_bounds__(1024) void dal_finalize(
    const float4* __restrict__ ws4, float* __restrict__ out)
{
    const int t    = (int)threadIdx.x;
    const int wv   = t >> 6;      // wave id == image id
    const int lane = t & 63;

    float4 a = ws4[2 * t];
    float4 b = ws4[2 * t + 1];
    float bce   = a.x + b.x;
    float inter = a.y + b.y;
    float sump  = a.z + b.z;
    float sumt  = a.w + b.w;

    #pragma unroll
    for (int off = 32; off > 0; off >>= 1) {
        bce   += __shfl_down(bce, off);
        inter += __shfl_down(inter, off);
        sump  += __shfl_down(sump, off);
        sumt  += __shfl_down(sumt, off);
    }

    __shared__ float sb[16], sd[16];
    if (lane == 0) {
        sb[wv] = bce;
        sd[wv] = 1.f - (2.f * inter + 1.f) / (sump + sumt + 1.f);
    }
    __syncthreads();
    if (t == 0) {
        float tb = 0.f, td = 0.f;
        #pragma unroll
        for (int i = 0; i < NIMG; ++i) { tb += sb[i]; td += sd[i]; }
        out[0] = tb / NPIX;
        out[1] = td / (float)NIMG;
    }
}

extern "C" void kernel_launch(void* const* d_in, const int* in_sizes, int n_in,
                              void* d_out, int out_size, void* d_ws, size_t ws_size,
                              hipStream_t stream)
{
    const float* x    = (const float*)d_in[0];  // boundary_logits [16,1,1024,1024]
    const float* g    = (const float*)d_in[1];  // gtmasks        [16,1024,1024]
    const float* fuse = (const float*)d_in[2];  // fuse_kernel    [3]
    float* out = (float*)d_out;
    float4* ws4 = (float4*)d_ws;

    dal_main<<<NBLK, 256, 0, stream>>>(x, g, fuse, ws4);
    dal_finalize<<<1, 1024, 0, stream>>>(ws4, out);
}

// Round 7
// 30.849 us; speedup vs baseline: 8.1611x; 1.0088x over previous
//
#include <hip/hip_runtime.h>

#define IMG_H 1024
#define IMG_W 1024
#define NIMG  16
#define NPIX  16777216.0f   // 16*1024*1024
#define SPI   128           // 8-row strips per image (1024/8)
#define NBLK  2048          // NIMG * SPI
#define LOG2E 1.44269504088896340736f
#define LN2   0.69314718055994530942f

// ws layout: one float4 per block: {bce, inter, sum_p, sum_t}. 2048*16B = 32 KB.

__global__ __launch_bounds__(256) void dal_main(
    const float* __restrict__ xlogits,
    const float* __restrict__ gmask,
    const float* __restrict__ fuse,
    float4* __restrict__ ws4)
{
    const int bid  = blockIdx.x;
    const int img  = bid >> 7;          // / SPI
    const int q    = bid & 127;
    const int r0   = q << 3;            // rows r0 .. r0+7, r0 % 8 == 0
    const int tid  = (int)threadIdx.x;
    const int lane = tid & 63;
    const int j0   = tid * 4;           // 4 cols per thread

    const float w0 = fuse[0], w1 = fuse[1], w2 = fuse[2];

    const size_t ibase = (size_t)img * (IMG_H * IMG_W);
    const float* gi = gmask + ibase;
    const float* xi = xlogits + ibase;

    // Overlapping-load halo scheme: per row, float4 at j0-1 and j0+1 (clamped
    // at edges, fixed up with cndmask). Covers cols j0-1 .. j0+4.
    const int  jl   = (j0 > 0) ? (j0 - 1) : 0;
    const int  jr1  = (j0 + 4 < IMG_W) ? (j0 + 1) : (IMG_W - 4);
    const bool hasL = (j0 > 0);
    const bool hasR = (j0 + 4 < IMG_W);

    // ---- Phase 1: issue ALL 28 loads in one straight-line block (max MLP).
    // OOB rows use a clamped address (valid memory); padding applied later.
    float4 ga[10], gb[10];
    #pragma unroll
    for (int t = 0; t < 10; ++t) {
        int r  = r0 - 1 + t;
        int rc = r < 0 ? 0 : (r > IMG_H - 1 ? IMG_H - 1 : r);
        const float* row = gi + (size_t)rc * IMG_W;
        ga[t] = *reinterpret_cast<const float4*>(row + jl);
        gb[t] = *reinterpret_cast<const float4*>(row + jr1);
    }
    const float* xrow = xi + (size_t)r0 * IMG_W + j0;
    float4 xv[8];
    #pragma unroll
    for (int r = 0; r < 8; ++r)
        xv[r] = *reinterpret_cast<const float4*>(xrow + (size_t)r * IMG_W);

    // ---- Phase 2: rowmins over (j0+k-1 .. j0+k+1) + center values.
    float rm[10][4];
    float cv[8][4];
    #pragma unroll
    for (int t = 0; t < 10; ++t) {
        float c0 = hasL ? ga[t].x : 0.f;      // col j0-1 (0 at left edge)
        float c1 = hasL ? ga[t].y : ga[t].x;  // col j0
        float c2 = hasL ? ga[t].z : ga[t].y;  // col j0+1
        float c3 = hasL ? ga[t].w : ga[t].z;  // col j0+2
        float c4 = hasR ? gb[t].z : gb[t].w;  // col j0+3
        float c5 = hasR ? gb[t].w : 0.f;      // col j0+4 (0 at right edge)
        rm[t][0] = fminf(c0, fminf(c1, c2));
        rm[t][1] = fminf(c1, fminf(c2, c3));
        rm[t][2] = fminf(c2, fminf(c3, c4));
        rm[t][3] = fminf(c3, fminf(c4, c5));
        if (t >= 1 && t <= 8) {
            cv[t - 1][0] = c1; cv[t - 1][1] = c2;
            cv[t - 1][2] = c3; cv[t - 1][3] = c4;
        }
    }
    // Vertical zero-padding (block-uniform): rowmin of an all-zero pad row is 0.
    if (r0 == 0)          { rm[0][0] = rm[0][1] = rm[0][2] = rm[0][3] = 0.f; }
    if (r0 == IMG_H - 8)  { rm[9][0] = rm[9][1] = rm[9][2] = rm[9][3] = 0.f; }

    // bt (stride-1 boundary map): bt = (g == 1) && (min3x3 == 0)
    float bt[8][4];
    #pragma unroll
    for (int r = 0; r < 8; ++r)
        #pragma unroll
        for (int k = 0; k < 4; ++k) {
            float cm = fminf(rm[r][k], fminf(rm[r + 1][k], rm[r + 2][k]));
            bt[r][k] = (cv[r][k] > 0.5f && cm < 0.5f) ? 1.f : 0.f;
        }

    // bt4: rows r0..r0+3 -> bt(r0, j0); rows r0+4..r0+7 -> bt(r0+4, j0)
    // bt2: bt(r0+(r&~1), j0+(k&~1));  base2[rp][kp] = w1*bt2 + w2*bt4
    const float wb4A = w2 * bt[0][0];
    const float wb4B = w2 * bt[4][0];
    float base2[4][2];
    #pragma unroll
    for (int rp = 0; rp < 4; ++rp) {
        const float wb = (rp < 2) ? wb4A : wb4B;
        base2[rp][0] = fmaf(w1, bt[2 * rp][0], wb);
        base2[rp][1] = fmaf(w1, bt[2 * rp][2], wb);
    }

    // Per-pixel: f = w0*bt + base2;  t = f > 0.1
    // bce_px = ln2*log2(1+e^x) - x*t ; p = u/(1+u), u = e^x
    // sum_t via ballot+popcount (SALU). Dual accumulators (row parity) for ILP.
    float l2[2]  = {0.f, 0.f}, xt[2] = {0.f, 0.f};
    float itr[2] = {0.f, 0.f}, sp[2] = {0.f, 0.f};
    int st = 0;

    auto px = [&](float x, float btv, float b2v, int a) {
        float f = fmaf(w0, btv, b2v);
        bool  c = f > 0.1f;
        st += (int)__popcll(__ballot(c));
        float u   = __builtin_amdgcn_exp2f(x * LOG2E);   // e^x
        float opu = 1.f + u;
        float p   = u * __builtin_amdgcn_rcpf(opu);      // sigmoid(x)
        l2[a]  += __builtin_amdgcn_logf(opu);            // log2(1+e^x)
        sp[a]  += p;
        xt[a]  += c ? x : 0.f;
        itr[a] += c ? p : 0.f;
    };

    #pragma unroll
    for (int r = 0; r < 8; ++r) {
        const int   rp = r >> 1;
        const int   a  = r & 1;
        const float bA = base2[rp][0];
        const float bB = base2[rp][1];
        px(xv[r].x, bt[r][0], bA, a);
        px(xv[r].y, bt[r][1], bA, a);
        px(xv[r].z, bt[r][2], bB, a);
        px(xv[r].w, bt[r][3], bB, a);
    }

    float bce   = fmaf(LN2, l2[0] + l2[1], -(xt[0] + xt[1]));
    float inter = itr[0] + itr[1];
    float sump  = sp[0] + sp[1];

    // wave64 reduce (st is wave-uniform via ballot), cross-wave via LDS
    #pragma unroll
    for (int off = 32; off > 0; off >>= 1) {
        bce   += __shfl_down(bce, off);
        inter += __shfl_down(inter, off);
        sump  += __shfl_down(sump, off);
    }
    __shared__ float red[4][4];
    const int wid = tid >> 6;
    if (lane == 0) {
        red[0][wid] = bce; red[1][wid] = inter;
        red[2][wid] = sump; red[3][wid] = (float)st;
    }
    __syncthreads();
    if (tid == 0) {
        float4 o;
        o.x = red[0][0] + red[0][1] + red[0][2] + red[0][3];
        o.y = red[1][0] + red[1][1] + red[1][2] + red[1][3];
        o.z = red[2][0] + red[2][1] + red[2][2] + red[2][3];
        o.w = red[3][0] + red[3][1] + red[3][2] + red[3][3];
        ws4[bid] = o;
    }
}

// 1 block, 1024 threads. Thread t loads slots 2t, 2t+1 (same image: both in
// [128w, 128w+128) for wave w = t>>6). Wave-reduce, per-image dice, combine.
__global__ __launch_bounds__(1024) void dal_finalize(
    const float4* __restrict__ ws4, float* __restrict__ out)
{
    const int t    = (int)threadIdx.x;
    const int wv   = t >> 6;      // wave id == image id
    const int lane = t & 63;

    float4 a = ws4[2 * t];
    float4 b = ws4[2 * t + 1];
    float bce   = a.x + b.x;
    float inter = a.y + b.y;
    float sump  = a.z + b.z;
    float sumt  = a.w + b.w;

    #pragma unroll
    for (int off = 32; off > 0; off >>= 1) {
        bce   += __shfl_down(bce, off);
        inter += __shfl_down(inter, off);
        sump  += __shfl_down(sump, off);
        sumt  += __shfl_down(sumt, off);
    }

    __shared__ float sb[16], sd[16];
    if (lane == 0) {
        sb[wv] = bce;
        sd[wv] = 1.f - (2.f * inter + 1.f) / (sump + sumt + 1.f);
    }
    __syncthreads();
    if (t == 0) {
        float tb = 0.f, td = 0.f;
        #pragma unroll
        for (int i = 0; i < NIMG; ++i) { tb += sb[i]; td += sd[i]; }
        out[0] = tb / NPIX;
        out[1] = td / (float)NIMG;
    }
}

extern "C" void kernel_launch(void* const* d_in, const int* in_sizes, int n_in,
                              void* d_out, int out_size, void* d_ws, size_t ws_size,
                              hipStream_t stream)
{
    const float* x    = (const float*)d_in[0];  // boundary_logits [16,1,1024,1024]
    const float* g    = (const float*)d_in[1];  // gtmasks        [16,1024,1024]
    const float* fuse = (const float*)d_in[2];  // fuse_kernel    [3]
    float* out = (float*)d_out;
    float4* ws4 = (float4*)d_ws;

    dal_main<<<NBLK, 256, 0, stream>>>(x, g, fuse, ws4);
    dal_finalize<<<1, 1024, 0, stream>>>(ws4, out);
}